// Round 19
// baseline (365.830 us; speedup 1.0000x reference)
//
#include <hip/hip_runtime.h>
#include <stdint.h>

#define T_  2048
#define H_  1024
#define NH_ 16
#define HD_ 64

typedef __bf16 bf16x8 __attribute__((ext_vector_type(8)));
typedef __bf16 bf16x4 __attribute__((ext_vector_type(4)));
typedef float  f32x4  __attribute__((ext_vector_type(4)));

__device__ __forceinline__ unsigned short f2bf(float f) {
  unsigned u = __builtin_bit_cast(unsigned, f);
  u += 0x7fffu + ((u >> 16) & 1u);          // RNE
  return (unsigned short)(u >> 16);
}

__device__ __forceinline__ uint2 pack4bf(float a, float b, float c, float d) {
  bf16x4 t;                                  // native casts -> v_cvt_pk_bf16_f32
  t[0] = (__bf16)a; t[1] = (__bf16)b; t[2] = (__bf16)c; t[3] = (__bf16)d;
  return __builtin_bit_cast(uint2, t);
}

// ---------------- fused: W_eff = W + 2*B@A (y=0..2, x4-vectorized) and x->bf16 (y=3) ----------------
__global__ __launch_bounds__(256) void prep_fused(
    const float* __restrict__ Wq, const float* __restrict__ Aq, const float* __restrict__ Bq,
    const float* __restrict__ Wk, const float* __restrict__ Ak, const float* __restrict__ Bk,
    const float* __restrict__ Wv, const float* __restrict__ Av, const float* __restrict__ Bv,
    const float* __restrict__ x,
    unsigned short* __restrict__ Weff, unsigned short* __restrict__ Xb) {
  int p = blockIdx.y;
  if (p == 3) {
#pragma unroll
    for (int j = 0; j < 4; ++j) {
      int chunk = blockIdx.x * 1024 + j * 256 + threadIdx.x;
      int i = chunk * 8;
      f32x4 a = *(const f32x4*)(x + i);
      f32x4 c = *(const f32x4*)(x + i + 4);
      uint4 rv;
      rv.x = (unsigned)f2bf(a[0]) | ((unsigned)f2bf(a[1]) << 16);
      rv.y = (unsigned)f2bf(a[2]) | ((unsigned)f2bf(a[3]) << 16);
      rv.z = (unsigned)f2bf(c[0]) | ((unsigned)f2bf(c[1]) << 16);
      rv.w = (unsigned)f2bf(c[2]) | ((unsigned)f2bf(c[3]) << 16);
      *(uint4*)(Xb + i) = rv;
    }
    return;
  }
  const float* W = (p == 0) ? Wq : (p == 1) ? Wk : Wv;
  const float* A = (p == 0) ? Aq : (p == 1) ? Ak : Av;
  const float* B = (p == 0) ? Bq : (p == 1) ? Bk : Bv;
  int idx4 = (blockIdx.x * 256 + threadIdx.x) * 4;
  int o = idx4 >> 10, h0 = idx4 & 1023;
  f32x4 acc = *(const f32x4*)(W + idx4);
#pragma unroll
  for (int r = 0; r < 8; ++r) {
    float bb = 2.0f * B[o * 8 + r];                  // SCALING = 16/8 = 2
    f32x4 av = *(const f32x4*)(A + r * H_ + h0);
#pragma unroll
    for (int j = 0; j < 4; ++j) acc[j] += bb * av[j];
  }
  uint2 pk;
  pk.x = (unsigned)f2bf(acc[0]) | ((unsigned)f2bf(acc[1]) << 16);
  pk.y = (unsigned)f2bf(acc[2]) | ((unsigned)f2bf(acc[3]) << 16);
  *(uint2*)(Weff + p * (H_ * H_) + idx4) = pk;
}

// ---------------- QKV GEMM: C[m,n] = sum_k Xb[m,k] * Weff[n,k] (+bias) ----------------
// R15 config: BK=64, 2 barriers/step, XOR chunk-swizzled LDS, swapped MFMA,
// XCD-chunked swizzle, __launch_bounds__(256,3) -> 3 blocks/CU.
#define BM 128
#define BN 128
#define BK 64
__global__ __launch_bounds__(256, 3) void gemm_qkv(
    const unsigned short* __restrict__ Xb, const unsigned short* __restrict__ Weff,
    const float* __restrict__ bq, const float* __restrict__ bk, const float* __restrict__ bv,
    const float* __restrict__ mask,
    unsigned short* __restrict__ qq, unsigned short* __restrict__ kk, unsigned short* __restrict__ vP) {
  __shared__ __align__(16) unsigned short As[BM][BK];   // 16 KB
  __shared__ __align__(16) unsigned short Bs[BM][BK];   // 16 KB
  int tid = threadIdx.x;
  int bid = blockIdx.x;                          // 1536
  int xcd = bid & 7, j = bid >> 3;               // XCD-chunked swizzle
  int mt = xcd * 8 + (j & 7);                    // m-tile 0..63
  int ntile = j >> 3;                            // n-tile 0..23
  int m0 = mt * BM;
  int n0 = ntile * BN;
  int w = tid >> 6, l = tid & 63;
  int wm = w >> 1, wn = w & 1;
  int lr = l & 15, lg = l >> 4;
  const float L2E = 1.4426950408889634f;

  f32x4 acc[4][4] = {};
#pragma unroll 1
  for (int kt = 0; kt < H_ / BK; ++kt) {
    __syncthreads();
#pragma unroll
    for (int i2 = 0; i2 < 4; ++i2) {
      int c = tid + i2 * 256;                    // 1024 16B chunks per operand tile
      int row = c >> 3, slot = c & 7;
      int ks = (slot ^ (row & 7)) * 8;           // inverse-swizzled global source
      const unsigned short* ga = Xb + (size_t)(m0 + row) * H_ + kt * BK + ks;
      const unsigned short* gb = Weff + (size_t)(n0 + row) * H_ + kt * BK + ks;
      __builtin_amdgcn_global_load_lds((const __attribute__((address_space(1))) void*)ga,
                                       (__attribute__((address_space(3))) void*)(&As[0][0] + c * 8), 16, 0, 0);
      __builtin_amdgcn_global_load_lds((const __attribute__((address_space(1))) void*)gb,
                                       (__attribute__((address_space(3))) void*)(&Bs[0][0] + c * 8), 16, 0, 0);
    }
    __syncthreads();                             // drain vmcnt: tile ready
#pragma unroll
    for (int kk2 = 0; kk2 < 2; ++kk2) {          // k-slice outer: live regs stay low
      bf16x8 af[4], bf[4];
#pragma unroll
      for (int f = 0; f < 4; ++f) {
        int ra = wm * 64 + f * 16 + lr;
        int rb = wn * 64 + f * 16 + lr;
        int sa = ((kk2 << 2) | lg) ^ (ra & 7);   // swizzled read chunk
        int sb = ((kk2 << 2) | lg) ^ (rb & 7);
        af[f] = *(const bf16x8*)&As[ra][sa * 8];
        bf[f] = *(const bf16x8*)&Bs[rb][sb * 8];
      }
#pragma unroll
      for (int fm = 0; fm < 4; ++fm)
#pragma unroll
        for (int fn = 0; fn < 4; ++fn)           // swapped: lanes=tokens(m), regs=features(n)
          acc[fm][fn] = __builtin_amdgcn_mfma_f32_16x16x32_bf16(bf[fn], af[fm], acc[fm][fn], 0, 0, 0);
    }
  }

  int p = n0 >> 10;
  const float* bias = (p == 0) ? bq : (p == 1) ? bk : bv;
  const float QSCALE = 0.125f * L2E;             // softmax 1/sqrt(64) and log2-base fold
#pragma unroll
  for (int fm = 0; fm < 4; ++fm) {
    int m = m0 + wm * 64 + fm * 16 + lr;
    int bb = m >> 11, t = m & 2047;
    float expm = (p == 2) ? exp2f(mask[(size_t)bb * T_ + t] * L2E) : 1.0f;  // e^{m[k]}
#pragma unroll
    for (int fn = 0; fn < 4; ++fn) {
      int o0 = (n0 & 1023) + wn * 64 + fn * 16 + lg * 4;
      int hh = o0 >> 6, d0 = o0 & 63;
      size_t bh = (size_t)(bb * NH_ + hh);
      f32x4 b4 = *(const f32x4*)(bias + o0);
      if (p == 0) {
        *(uint2*)(qq + (bh * T_ + t) * HD_ + d0) =
          pack4bf((acc[fm][fn][0] + b4[0]) * QSCALE, (acc[fm][fn][1] + b4[1]) * QSCALE,
                  (acc[fm][fn][2] + b4[2]) * QSCALE, (acc[fm][fn][3] + b4[3]) * QSCALE);
      } else if (p == 1) {
        *(uint2*)(kk + (bh * T_ + t) * HD_ + d0) =
          pack4bf(acc[fm][fn][0] + b4[0], acc[fm][fn][1] + b4[1],
                  acc[fm][fn][2] + b4[2], acc[fm][fn][3] + b4[3]);
      } else {
        int r5 = t & 31;
        int within = ((r5 >> 2) & 3) * 8 + (r5 & 3) + ((r5 >> 4) << 2);
        size_t tbase = (size_t)(t & ~31) + within;
#pragma unroll
        for (int r = 0; r < 4; ++r)
          vP[(bh * HD_ + d0 + r) * T_ + tbase] =
            __builtin_bit_cast(unsigned short, (__bf16)((acc[fm][fn][r] + b4[r]) * expm));
      }
    }
  }
}

// ---------------- causal flash attention: K in LDS, V direct from global (L2) ----------------
// R16 structure: block (bh,i) = 4 waves on q-tiles {4i..4i+3}, lockstep k-tiles
// 0..i, 2048 blocks big-first, __syncthreads sync. NEW: V is NOT staged — vP's
// permuted layout makes the PV A-fragment one contiguous 16B global load (L2:
// 2 MB V per XCD). LDS = K dbuf 16 KB + cbuf 4 KB = 20 KB -> 6 blocks/CU
// ((256,6), reg cap 85 vs ~70 used). Staging per tile halves -> barrier drain halves.
__global__ __launch_bounds__(256, 6) void attn_fwd(
    const unsigned short* __restrict__ qq, const unsigned short* __restrict__ kk,
    const unsigned short* __restrict__ vP, const float* __restrict__ mask,
    float* __restrict__ out) {
  __shared__ __align__(16) char lds[2][8192];    // K only: [buf][sub0 4K | sub1 4K]
  __shared__ __align__(16) char cbuf[4096];      // exp(mask), permuted, all 2048 keys

  int tid = threadIdx.x;
  int w = tid >> 6, l = tid & 63;
  int bid = blockIdx.x;                          // 2048
  int bh = bid & 63;                             // bid%8==bh&7 -> XCD locality
  int i = 31 - (bid >> 6);                       // big groups dispatch first
  int b = bh >> 4, h = bh & 15;
  int lr = l & 15, g8 = l >> 4;
  const float L2E = 1.4426950408889634f;
  const float NINF = -__builtin_inff();

  const unsigned short* Kp = kk + (size_t)bh * T_ * HD_;
  const unsigned short* Vp = vP + (size_t)bh * HD_ * T_;
  const float* mp = mask + b * T_;

  int krow = tid >> 3, kslot = tid & 7;
  int kgs = kslot ^ (krow & 7);

  auto stage32 = [&](int t32, int dst, int sub) {
    int k0 = t32 * 32;
    const unsigned short* srcK = Kp + (size_t)(k0 + krow) * HD_ + kgs * 8;
    __builtin_amdgcn_global_load_lds((const __attribute__((address_space(1))) void*)srcK,
        (__attribute__((address_space(3))) void*)(&lds[dst][sub * 4096 + tid * 16]), 16, 0, 0);
  };
  auto stage64 = [&](int t64, int dst) { stage32(2 * t64, dst, 0); stage32(2 * t64 + 1, dst, 1); };

  int kswz = lr & 7;

  int qt = 4 * i + w;
  int ntmax64 = i + 1;
  int nt = (qt >> 1) + 1;                        // 32-key tiles; nfull == i for all waves
  int dsub = (nt - 1) & 1;
  int t0 = qt * 16;
  const unsigned short* Qp = qq + ((size_t)bh * T_ + t0) * HD_;

  bf16x8 qf[2];
#pragma unroll
  for (int hs = 0; hs < 2; ++hs)
    qf[hs] = *(const bf16x8*)(Qp + lr * HD_ + hs * 32 + g8 * 8);

  f32x4 accO[4] = {};
  f32x4 accL = {};

  auto qk32 = [&](const char* kb, f32x4& s0, f32x4& s1) {
#pragma unroll
    for (int hs = 0; hs < 2; ++hs) {
      int sl = ((hs << 2) | g8) ^ kswz;
      bf16x8 kc0 = *(const bf16x8*)(kb + lr * 128 + (sl << 4));
      bf16x8 kc1 = *(const bf16x8*)(kb + (16 + lr) * 128 + (sl << 4));
      __builtin_amdgcn_s_setprio(1);
      s0 = __builtin_amdgcn_mfma_f32_16x16x32_bf16(kc0, qf[hs], s0, 0, 0, 0);
      s1 = __builtin_amdgcn_mfma_f32_16x16x32_bf16(kc1, qf[hs], s1, 0, 0, 0);
      __builtin_amdgcn_s_setprio(0);
    }
  };
  auto pv32 = [&](const bf16x8 (&vf)[4], bf16x8 pv) {
#pragma unroll
    for (int dn = 0; dn < 4; ++dn) {
      __builtin_amdgcn_s_setprio(1);
      accO[dn] = __builtin_amdgcn_mfma_f32_16x16x32_bf16(vf[dn], pv, accO[dn], 0, 0, 0);
      __builtin_amdgcn_s_setprio(0);
    }
  };
  auto loadV = [&](int k0, bf16x8 (&vf)[4]) {     // direct global, L2-resident
#pragma unroll
    for (int dn = 0; dn < 4; ++dn)
      vf[dn] = *(const bf16x8*)(Vp + (size_t)(dn * 16 + lr) * T_ + k0 + g8 * 8);
  };

  auto step64 = [&](const char* kb0, const char* kb1, int k0) {
    bf16x8 vfA[4], vfB[4];
    loadV(k0, vfA);                               // issue early: hides under QK MFMAs
    loadV(k0 + 32, vfB);
    f32x4 sA0 = {}, sA1 = {}, sB0 = {}, sB1 = {};
    qk32(kb0, sA0, sA1);
    qk32(kb1, sB0, sB1);
    bf16x8 pvA, pvB;
#pragma unroll
    for (int r = 0; r < 4; ++r) {
      pvA[r]     = (__bf16)exp2f(sA0[r]);
      pvA[4 + r] = (__bf16)exp2f(sA1[r]);
      pvB[r]     = (__bf16)exp2f(sB0[r]);
      pvB[4 + r] = (__bf16)exp2f(sB1[r]);
    }
    bf16x8 cf0 = *(const bf16x8*)(&cbuf[(k0 >> 5) * 64 + g8 * 16]);
    bf16x8 cf1 = *(const bf16x8*)(&cbuf[(k0 >> 5) * 64 + 64 + g8 * 16]);
    __builtin_amdgcn_s_setprio(1);
    accL = __builtin_amdgcn_mfma_f32_16x16x32_bf16(cf0, pvA, accL, 0, 0, 0);
    accL = __builtin_amdgcn_mfma_f32_16x16x32_bf16(cf1, pvB, accL, 0, 0, 0);
    __builtin_amdgcn_s_setprio(0);
    pv32(vfA, pvA);
    pv32(vfB, pvB);
  };

  auto step32 = [&](const char* kb, int k0, bool diag) {
    bf16x8 vf[4];
    loadV(k0, vf);
    f32x4 s0 = {}, s1 = {};
    qk32(kb, s0, s1);
    bf16x8 pv;
    int qrow = t0 + lr;
#pragma unroll
    for (int r = 0; r < 4; ++r) {
      int ka = k0 + g8 * 4 + r;
      float a0 = (!diag || ka <= qrow)      ? s0[r] : NINF;
      float a1 = (!diag || ka + 16 <= qrow) ? s1[r] : NINF;
      pv[r]     = (__bf16)exp2f(a0);
      pv[4 + r] = (__bf16)exp2f(a1);
    }
    bf16x8 cf = *(const bf16x8*)(&cbuf[(k0 >> 5) * 64 + g8 * 16]);
    __builtin_amdgcn_s_setprio(1);
    accL = __builtin_amdgcn_mfma_f32_16x16x32_bf16(cf, pv, accL, 0, 0, 0);
    __builtin_amdgcn_s_setprio(0);
    pv32(vf, pv);
  };

  // ---- prologue: stage K tile 0 + build cbuf; one full drain ----
  int buf = 0;
  stage64(0, 0);
  {
    int tt = tid >> 2, q8 = tid & 3;
    int base0 = tt * 32 + q8 * 4;
    f32x4 mlo = *(const f32x4*)(mp + base0);
    f32x4 mhi = *(const f32x4*)(mp + base0 + 16);
    bf16x8 cf;
#pragma unroll
    for (int r = 0; r < 4; ++r) {
      cf[r]     = (__bf16)exp2f(mlo[r] * L2E);
      cf[4 + r] = (__bf16)exp2f(mhi[r] * L2E);
    }
    *(bf16x8*)(&cbuf[tid * 16]) = cf;
  }
  __syncthreads();

#pragma unroll 1
  for (int ti = 0; ti < ntmax64; ++ti) {
    if (ti + 1 < ntmax64) stage64(ti + 1, buf ^ 1);
    const char* kb0 = lds[buf];
    const char* kb1 = lds[buf] + 4096;
    if (ti < ntmax64 - 1) {
      step64(kb0, kb1, ti * 64);
    } else {                                     // last tile (== i) has the diagonal
      if (dsub == 0) {
        step32(kb0, ti * 64, true);
      } else {
        step32(kb0, ti * 64, false);
        step32(kb1, ti * 64 + 32, true);
      }
    }
    __syncthreads();
    buf ^= 1;
  }

  float inv = 1.0f / accL[0];                    // complete per-q sum, all lanes
  float* op = out + ((size_t)b * T_ + t0 + lr) * H_ + h * HD_;
#pragma unroll
  for (int dn = 0; dn < 4; ++dn) {
    f32x4 ov;
#pragma unroll
    for (int r = 0; r < 4; ++r) ov[r] = accO[dn][r] * inv;
    *(f32x4*)(op + dn * 16 + g8 * 4) = ov;
  }
}

extern "C" void kernel_launch(void* const* d_in, const int* in_sizes, int n_in,
                              void* d_out, int out_size, void* d_ws, size_t ws_size,
                              hipStream_t stream) {
  const float* x    = (const float*)d_in[0];
  const float* mask = (const float*)d_in[1];
  const float* Wq = (const float*)d_in[2];
  const float* bq = (const float*)d_in[3];
  const float* Aq = (const float*)d_in[4];
  const float* Bq = (const float*)d_in[5];
  const float* Wk = (const float*)d_in[6];
  const float* bk = (const float*)d_in[7];
  const float* Ak = (const float*)d_in[8];
  const float* Bk = (const float*)d_in[9];
  const float* Wv = (const float*)d_in[10];
  const float* bv = (const float*)d_in[11];
  const float* Av = (const float*)d_in[12];
  const float* Bv = (const float*)d_in[13];
  float* out = (float*)d_out;

  char* ws = (char*)d_ws;
  unsigned short* Xb   = (unsigned short*)(ws);                   // 16 MB  [8192][1024]
  unsigned short* Weff = (unsigned short*)(ws + (16u << 20));     //  6 MB  [3][1024][1024]
  unsigned short* qq   = (unsigned short*)(ws + (22u << 20));     // 16 MB  [4][16][2048][64]
  unsigned short* kk   = (unsigned short*)(ws + (38u << 20));     // 16 MB  [4][16][2048][64]
  unsigned short* vP   = (unsigned short*)(ws + (54u << 20));     // 16 MB  [4][16][64][2048] (permuted, mask-folded)

  prep_fused<<<dim3(1024, 4), 256, 0, stream>>>(Wq, Aq, Bq, Wk, Ak, Bk, Wv, Av, Bv, x, Weff, Xb);
  gemm_qkv<<<1536, 256, 0, stream>>>(Xb, Weff, bq, bk, bv, mask, qq, kk, vP);
  attn_fwd<<<2048, 256, 0, stream>>>(qq, kk, vP, mask, out);
}

// Round 20
// 143.995 us; speedup vs baseline: 2.5406x; 2.5406x over previous
//
#include <hip/hip_runtime.h>
#include <stdint.h>

#define T_  2048
#define H_  1024
#define NH_ 16
#define HD_ 64

typedef __bf16 bf16x8 __attribute__((ext_vector_type(8)));
typedef __bf16 bf16x4 __attribute__((ext_vector_type(4)));
typedef float  f32x4  __attribute__((ext_vector_type(4)));

__device__ __forceinline__ unsigned short f2bf(float f) {
  unsigned u = __builtin_bit_cast(unsigned, f);
  u += 0x7fffu + ((u >> 16) & 1u);          // RNE
  return (unsigned short)(u >> 16);
}

__device__ __forceinline__ uint2 pack4bf(float a, float b, float c, float d) {
  bf16x4 t;                                  // native casts -> v_cvt_pk_bf16_f32
  t[0] = (__bf16)a; t[1] = (__bf16)b; t[2] = (__bf16)c; t[3] = (__bf16)d;
  return __builtin_bit_cast(uint2, t);
}

// ---------------- fused: W_eff = W + 2*B@A (y=0..2), x->bf16 + cfP table (y=3) ----------------
__global__ __launch_bounds__(256) void prep_fused(
    const float* __restrict__ Wq, const float* __restrict__ Aq, const float* __restrict__ Bq,
    const float* __restrict__ Wk, const float* __restrict__ Ak, const float* __restrict__ Bk,
    const float* __restrict__ Wv, const float* __restrict__ Av, const float* __restrict__ Bv,
    const float* __restrict__ x, const float* __restrict__ mask,
    unsigned short* __restrict__ Weff, unsigned short* __restrict__ Xb,
    unsigned short* __restrict__ cfP) {
  int p = blockIdx.y;
  const float L2E = 1.4426950408889634f;
  if (p == 3) {
#pragma unroll
    for (int j = 0; j < 4; ++j) {
      int chunk = blockIdx.x * 1024 + j * 256 + threadIdx.x;
      int i = chunk * 8;
      f32x4 a = *(const f32x4*)(x + i);
      f32x4 c = *(const f32x4*)(x + i + 4);
      uint4 rv;
      rv.x = (unsigned)f2bf(a[0]) | ((unsigned)f2bf(a[1]) << 16);
      rv.y = (unsigned)f2bf(a[2]) | ((unsigned)f2bf(a[3]) << 16);
      rv.z = (unsigned)f2bf(c[0]) | ((unsigned)f2bf(c[1]) << 16);
      rv.w = (unsigned)f2bf(c[2]) | ((unsigned)f2bf(c[3]) << 16);
      *(uint4*)(Xb + i) = rv;
    }
    if (blockIdx.x < 4) {
      // cfP[b][2048]: exp(mask) in the attn-permuted bf16x8 layout
      int bb = blockIdx.x;
      int j = threadIdx.x;                    // covers keys tile=(j>>2), q8=(j&3)
      int base0 = (j >> 2) * 32 + (j & 3) * 4;
      const float* mpb = mask + bb * T_;
      f32x4 mlo = *(const f32x4*)(mpb + base0);
      f32x4 mhi = *(const f32x4*)(mpb + base0 + 16);
      bf16x8 cf;
#pragma unroll
      for (int r = 0; r < 4; ++r) {
        cf[r]     = (__bf16)exp2f(mlo[r] * L2E);
        cf[4 + r] = (__bf16)exp2f(mhi[r] * L2E);
      }
      *(bf16x8*)(cfP + bb * 2048 + j * 8) = cf;
    }
    return;
  }
  const float* W = (p == 0) ? Wq : (p == 1) ? Wk : Wv;
  const float* A = (p == 0) ? Aq : (p == 1) ? Ak : Av;
  const float* B = (p == 0) ? Bq : (p == 1) ? Bk : Bv;
  int idx4 = (blockIdx.x * 256 + threadIdx.x) * 4;
  int o = idx4 >> 10, h0 = idx4 & 1023;
  f32x4 acc = *(const f32x4*)(W + idx4);
#pragma unroll
  for (int r = 0; r < 8; ++r) {
    float bb = 2.0f * B[o * 8 + r];                  // SCALING = 16/8 = 2
    f32x4 av = *(const f32x4*)(A + r * H_ + h0);
#pragma unroll
    for (int j = 0; j < 4; ++j) acc[j] += bb * av[j];
  }
  uint2 pk;
  pk.x = (unsigned)f2bf(acc[0]) | ((unsigned)f2bf(acc[1]) << 16);
  pk.y = (unsigned)f2bf(acc[2]) | ((unsigned)f2bf(acc[3]) << 16);
  *(uint2*)(Weff + p * (H_ * H_) + idx4) = pk;
}

// ---------------- QKV GEMM: C[m,n] = sum_k Xb[m,k] * Weff[n,k] (+bias) ----------------
// R15 config: BK=64, 2 barriers/step, XOR chunk-swizzled LDS, swapped MFMA,
// XCD-chunked swizzle, __launch_bounds__(256,3) -> 3 blocks/CU.
#define BM 128
#define BN 128
#define BK 64
__global__ __launch_bounds__(256, 3) void gemm_qkv(
    const unsigned short* __restrict__ Xb, const unsigned short* __restrict__ Weff,
    const float* __restrict__ bq, const float* __restrict__ bk, const float* __restrict__ bv,
    const float* __restrict__ mask,
    unsigned short* __restrict__ qq, unsigned short* __restrict__ kk, unsigned short* __restrict__ vP) {
  __shared__ __align__(16) unsigned short As[BM][BK];   // 16 KB
  __shared__ __align__(16) unsigned short Bs[BM][BK];   // 16 KB
  int tid = threadIdx.x;
  int bid = blockIdx.x;                          // 1536
  int xcd = bid & 7, j = bid >> 3;               // XCD-chunked swizzle
  int mt = xcd * 8 + (j & 7);                    // m-tile 0..63
  int ntile = j >> 3;                            // n-tile 0..23
  int m0 = mt * BM;
  int n0 = ntile * BN;
  int w = tid >> 6, l = tid & 63;
  int wm = w >> 1, wn = w & 1;
  int lr = l & 15, lg = l >> 4;
  const float L2E = 1.4426950408889634f;

  f32x4 acc[4][4] = {};
#pragma unroll 1
  for (int kt = 0; kt < H_ / BK; ++kt) {
    __syncthreads();
#pragma unroll
    for (int i2 = 0; i2 < 4; ++i2) {
      int c = tid + i2 * 256;                    // 1024 16B chunks per operand tile
      int row = c >> 3, slot = c & 7;
      int ks = (slot ^ (row & 7)) * 8;           // inverse-swizzled global source
      const unsigned short* ga = Xb + (size_t)(m0 + row) * H_ + kt * BK + ks;
      const unsigned short* gb = Weff + (size_t)(n0 + row) * H_ + kt * BK + ks;
      __builtin_amdgcn_global_load_lds((const __attribute__((address_space(1))) void*)ga,
                                       (__attribute__((address_space(3))) void*)(&As[0][0] + c * 8), 16, 0, 0);
      __builtin_amdgcn_global_load_lds((const __attribute__((address_space(1))) void*)gb,
                                       (__attribute__((address_space(3))) void*)(&Bs[0][0] + c * 8), 16, 0, 0);
    }
    __syncthreads();                             // drain vmcnt: tile ready
#pragma unroll
    for (int kk2 = 0; kk2 < 2; ++kk2) {          // k-slice outer: live regs stay low
      bf16x8 af[4], bf[4];
#pragma unroll
      for (int f = 0; f < 4; ++f) {
        int ra = wm * 64 + f * 16 + lr;
        int rb = wn * 64 + f * 16 + lr;
        int sa = ((kk2 << 2) | lg) ^ (ra & 7);   // swizzled read chunk
        int sb = ((kk2 << 2) | lg) ^ (rb & 7);
        af[f] = *(const bf16x8*)&As[ra][sa * 8];
        bf[f] = *(const bf16x8*)&Bs[rb][sb * 8];
      }
#pragma unroll
      for (int fm = 0; fm < 4; ++fm)
#pragma unroll
        for (int fn = 0; fn < 4; ++fn)           // swapped: lanes=tokens(m), regs=features(n)
          acc[fm][fn] = __builtin_amdgcn_mfma_f32_16x16x32_bf16(bf[fn], af[fm], acc[fm][fn], 0, 0, 0);
    }
  }

  int p = n0 >> 10;
  const float* bias = (p == 0) ? bq : (p == 1) ? bk : bv;
  const float QSCALE = 0.125f * L2E;             // softmax 1/sqrt(64) and log2-base fold
#pragma unroll
  for (int fm = 0; fm < 4; ++fm) {
    int m = m0 + wm * 64 + fm * 16 + lr;
    int bb = m >> 11, t = m & 2047;
    float expm = (p == 2) ? exp2f(mask[(size_t)bb * T_ + t] * L2E) : 1.0f;  // e^{m[k]}
#pragma unroll
    for (int fn = 0; fn < 4; ++fn) {
      int o0 = (n0 & 1023) + wn * 64 + fn * 16 + lg * 4;
      int hh = o0 >> 6, d0 = o0 & 63;
      size_t bh = (size_t)(bb * NH_ + hh);
      f32x4 b4 = *(const f32x4*)(bias + o0);
      if (p == 0) {
        *(uint2*)(qq + (bh * T_ + t) * HD_ + d0) =
          pack4bf((acc[fm][fn][0] + b4[0]) * QSCALE, (acc[fm][fn][1] + b4[1]) * QSCALE,
                  (acc[fm][fn][2] + b4[2]) * QSCALE, (acc[fm][fn][3] + b4[3]) * QSCALE);
      } else if (p == 1) {
        *(uint2*)(kk + (bh * T_ + t) * HD_ + d0) =
          pack4bf(acc[fm][fn][0] + b4[0], acc[fm][fn][1] + b4[1],
                  acc[fm][fn][2] + b4[2], acc[fm][fn][3] + b4[3]);
      } else {
        int r5 = t & 31;
        int within = ((r5 >> 2) & 3) * 8 + (r5 & 3) + ((r5 >> 4) << 2);
        size_t tbase = (size_t)(t & ~31) + within;
#pragma unroll
        for (int r = 0; r < 4; ++r)
          vP[(bh * HD_ + d0 + r) * T_ + tbase] =
            __builtin_bit_cast(unsigned short, (__bf16)((acc[fm][fn][r] + b4[r]) * expm));
      }
    }
  }
}

// ---------------- causal flash attention, LDS K/V, KVBLK=64 ----------------
// One q-group per block: block (bh,i) = 4 waves on q-tiles {4i..4i+3}, lockstep
// k-tiles 0..i (zero divergence: nfull=i for all waves). 2048 blocks big-first
// (i descending) + over-subscription -> greedy backfill balances CUs.
// LDS exactly 32 KB -> 5 blocks/CU; (256,5). cf table read from global (L2).
// Base-2 softmax, no reference; mask folded into V'; l on the MFMA pipe.
__global__ __launch_bounds__(256, 5) void attn_fwd(
    const unsigned short* __restrict__ qq, const unsigned short* __restrict__ kk,
    const unsigned short* __restrict__ vP, const unsigned short* __restrict__ cfP,
    float* __restrict__ out) {
  __shared__ __align__(16) char lds[2][16384];   // [buf][sub0: K4K|V4K | sub1: K4K|V4K] = 32 KB

  int tid = threadIdx.x;
  int w = tid >> 6, l = tid & 63;
  int bid = blockIdx.x;                          // 2048
  int bh = bid & 63;                             // bid%8==bh&7 -> XCD locality
  int i = 31 - (bid >> 6);                       // big groups dispatch first
  int b = bh >> 4, h = bh & 15;
  int lr = l & 15, g8 = l >> 4;
  const float NINF = -__builtin_inff();

  const unsigned short* Kp = kk + (size_t)bh * T_ * HD_;
  const unsigned short* Vp = vP + (size_t)bh * HD_ * T_;
  const unsigned short* cfb = cfP + b * 2048;

  int krow = tid >> 3, kslot = tid & 7;
  int kgs = kslot ^ (krow & 7);
  int vsub = kgs >> 2, vslot = kgs & 3;
  int vrow = (krow << 1) | vsub;

  auto stage32 = [&](int t32, int dst, int sub) {
    int k0 = t32 * 32;
    const unsigned short* srcK = Kp + (size_t)(k0 + krow) * HD_ + kgs * 8;
    __builtin_amdgcn_global_load_lds((const __attribute__((address_space(1))) void*)srcK,
        (__attribute__((address_space(3))) void*)(&lds[dst][sub * 8192 + tid * 16]), 16, 0, 0);
    const unsigned short* srcV = Vp + (size_t)vrow * T_ + k0 + vslot * 8;
    __builtin_amdgcn_global_load_lds((const __attribute__((address_space(1))) void*)srcV,
        (__attribute__((address_space(3))) void*)(&lds[dst][sub * 8192 + 4096 + tid * 16]), 16, 0, 0);
  };
  auto stage64 = [&](int t64, int dst) { stage32(2 * t64, dst, 0); stage32(2 * t64 + 1, dst, 1); };

  int kswz = lr & 7;
  int vrd = (lr >> 1) & 7;

  int qt = 4 * i + w;
  int ntmax64 = i + 1;
  int nt = (qt >> 1) + 1;                        // 32-key tiles; nfull == i for all waves
  int dsub = (nt - 1) & 1;
  int t0 = qt * 16;
  const unsigned short* Qp = qq + ((size_t)bh * T_ + t0) * HD_;

  bf16x8 qf[2];
#pragma unroll
  for (int hs = 0; hs < 2; ++hs)
    qf[hs] = *(const bf16x8*)(Qp + lr * HD_ + hs * 32 + g8 * 8);

  f32x4 accO[4] = {};
  f32x4 accL = {};

  auto qk32 = [&](const char* kb, f32x4& s0, f32x4& s1) {
#pragma unroll
    for (int hs = 0; hs < 2; ++hs) {
      int sl = ((hs << 2) | g8) ^ kswz;
      bf16x8 kc0 = *(const bf16x8*)(kb + lr * 128 + (sl << 4));
      bf16x8 kc1 = *(const bf16x8*)(kb + (16 + lr) * 128 + (sl << 4));
      __builtin_amdgcn_s_setprio(1);
      s0 = __builtin_amdgcn_mfma_f32_16x16x32_bf16(kc0, qf[hs], s0, 0, 0, 0);
      s1 = __builtin_amdgcn_mfma_f32_16x16x32_bf16(kc1, qf[hs], s1, 0, 0, 0);
      __builtin_amdgcn_s_setprio(0);
    }
  };
  auto pv32 = [&](const char* kb, bf16x8 pv) {
#pragma unroll
    for (int dn = 0; dn < 4; ++dn) {
      int rowp = dn * 8 + (lr >> 1);
      int sl = (((lr & 1) << 2) | g8) ^ vrd;
      bf16x8 vf = *(const bf16x8*)(kb + 4096 + rowp * 128 + (sl << 4));
      __builtin_amdgcn_s_setprio(1);
      accO[dn] = __builtin_amdgcn_mfma_f32_16x16x32_bf16(vf, pv, accO[dn], 0, 0, 0);
      __builtin_amdgcn_s_setprio(0);
    }
  };

  auto step64 = [&](const char* kb0, const char* kb1, int k0) {
    f32x4 sA0 = {}, sA1 = {}, sB0 = {}, sB1 = {};
    qk32(kb0, sA0, sA1);
    qk32(kb1, sB0, sB1);
    bf16x8 pvA, pvB;
#pragma unroll
    for (int r = 0; r < 4; ++r) {
      pvA[r]     = (__bf16)exp2f(sA0[r]);
      pvA[4 + r] = (__bf16)exp2f(sA1[r]);
      pvB[r]     = (__bf16)exp2f(sB0[r]);
      pvB[4 + r] = (__bf16)exp2f(sB1[r]);
    }
    bf16x8 cf0 = *(const bf16x8*)(cfb + (k0 >> 5) * 32 + g8 * 8);
    bf16x8 cf1 = *(const bf16x8*)(cfb + (k0 >> 5) * 32 + 32 + g8 * 8);
    __builtin_amdgcn_s_setprio(1);
    accL = __builtin_amdgcn_mfma_f32_16x16x32_bf16(cf0, pvA, accL, 0, 0, 0);
    accL = __builtin_amdgcn_mfma_f32_16x16x32_bf16(cf1, pvB, accL, 0, 0, 0);
    __builtin_amdgcn_s_setprio(0);
    pv32(kb0, pvA);
    pv32(kb1, pvB);
  };

  auto step32 = [&](const char* kb, int k0, bool diag) {
    f32x4 s0 = {}, s1 = {};
    qk32(kb, s0, s1);
    bf16x8 pv;
    int qrow = t0 + lr;
#pragma unroll
    for (int r = 0; r < 4; ++r) {
      int ka = k0 + g8 * 4 + r;
      float a0 = (!diag || ka <= qrow)      ? s0[r] : NINF;
      float a1 = (!diag || ka + 16 <= qrow) ? s1[r] : NINF;
      pv[r]     = (__bf16)exp2f(a0);
      pv[4 + r] = (__bf16)exp2f(a1);
    }
    bf16x8 cf = *(const bf16x8*)(cfb + (k0 >> 5) * 32 + g8 * 8);
    __builtin_amdgcn_s_setprio(1);
    accL = __builtin_amdgcn_mfma_f32_16x16x32_bf16(cf, pv, accL, 0, 0, 0);
    __builtin_amdgcn_s_setprio(0);
    pv32(kb, pv);
  };

  int buf = 0;
  stage64(0, 0);
  __syncthreads();

#pragma unroll 1
  for (int ti = 0; ti < ntmax64; ++ti) {
    if (ti + 1 < ntmax64) stage64(ti + 1, buf ^ 1);
    const char* kb0 = lds[buf];
    const char* kb1 = lds[buf] + 8192;
    if (ti < ntmax64 - 1) {
      step64(kb0, kb1, ti * 64);
    } else {                                     // ti == nfull == i (all waves)
      if (dsub == 0) {
        step32(kb0, ti * 64, true);
      } else {
        step32(kb0, ti * 64, false);
        step32(kb1, ti * 64 + 32, true);
      }
    }
    __syncthreads();
    buf ^= 1;
  }

  float inv = 1.0f / accL[0];                    // complete per-q sum, all lanes
  float* op = out + ((size_t)b * T_ + t0 + lr) * H_ + h * HD_;
#pragma unroll
  for (int dn = 0; dn < 4; ++dn) {
    f32x4 ov;
#pragma unroll
    for (int r = 0; r < 4; ++r) ov[r] = accO[dn][r] * inv;
    *(f32x4*)(op + dn * 16 + g8 * 4) = ov;
  }
}

extern "C" void kernel_launch(void* const* d_in, const int* in_sizes, int n_in,
                              void* d_out, int out_size, void* d_ws, size_t ws_size,
                              hipStream_t stream) {
  const float* x    = (const float*)d_in[0];
  const float* mask = (const float*)d_in[1];
  const float* Wq = (const float*)d_in[2];
  const float* bq = (const float*)d_in[3];
  const float* Aq = (const float*)d_in[4];
  const float* Bq = (const float*)d_in[5];
  const float* Wk = (const float*)d_in[6];
  const float* bk = (const float*)d_in[7];
  const float* Ak = (const float*)d_in[8];
  const float* Bk = (const float*)d_in[9];
  const float* Wv = (const float*)d_in[10];
  const float* bv = (const float*)d_in[11];
  const float* Av = (const float*)d_in[12];
  const float* Bv = (const float*)d_in[13];
  float* out = (float*)d_out;

  char* ws = (char*)d_ws;
  unsigned short* Xb   = (unsigned short*)(ws);                   // 16 MB  [8192][1024]
  unsigned short* Weff = (unsigned short*)(ws + (16u << 20));     //  6 MB  [3][1024][1024]
  unsigned short* qq   = (unsigned short*)(ws + (22u << 20));     // 16 MB  [4][16][2048][64]
  unsigned short* kk   = (unsigned short*)(ws + (38u << 20));     // 16 MB  [4][16][2048][64]
  unsigned short* vP   = (unsigned short*)(ws + (54u << 20));     // 16 MB  [4][16][64][2048] (permuted, mask-folded)
  unsigned short* cfP  = (unsigned short*)(ws + (70u << 20));     // 16 KB  [4][2048] exp(mask), permuted

  prep_fused<<<dim3(1024, 4), 256, 0, stream>>>(Wq, Aq, Bq, Wk, Ak, Bk, Wv, Av, Bv, x, mask, Weff, Xb, cfP);
  gemm_qkv<<<1536, 256, 0, stream>>>(Xb, Weff, bq, bk, bv, mask, qq, kk, vP);
  attn_fwd<<<2048, 256, 0, stream>>>(qq, kk, vP, cfP, out);
}

// Round 21
// 141.906 us; speedup vs baseline: 2.5780x; 1.0147x over previous
//
#include <hip/hip_runtime.h>
#include <stdint.h>

#define T_  2048
#define H_  1024
#define NH_ 16
#define HD_ 64

typedef __bf16 bf16x8 __attribute__((ext_vector_type(8)));
typedef __bf16 bf16x4 __attribute__((ext_vector_type(4)));
typedef float  f32x4  __attribute__((ext_vector_type(4)));

__device__ __forceinline__ unsigned short f2bf(float f) {
  unsigned u = __builtin_bit_cast(unsigned, f);
  u += 0x7fffu + ((u >> 16) & 1u);          // RNE
  return (unsigned short)(u >> 16);
}

__device__ __forceinline__ uint2 pack4bf(float a, float b, float c, float d) {
  bf16x4 t;                                  // native casts -> v_cvt_pk_bf16_f32
  t[0] = (__bf16)a; t[1] = (__bf16)b; t[2] = (__bf16)c; t[3] = (__bf16)d;
  return __builtin_bit_cast(uint2, t);
}

// ---------------- fused: W_eff = W + 2*B@A (y=0..2), x->bf16 + cfP table (y=3) ----------------
__global__ __launch_bounds__(256) void prep_fused(
    const float* __restrict__ Wq, const float* __restrict__ Aq, const float* __restrict__ Bq,
    const float* __restrict__ Wk, const float* __restrict__ Ak, const float* __restrict__ Bk,
    const float* __restrict__ Wv, const float* __restrict__ Av, const float* __restrict__ Bv,
    const float* __restrict__ x, const float* __restrict__ mask,
    unsigned short* __restrict__ Weff, unsigned short* __restrict__ Xb,
    unsigned short* __restrict__ cfP) {
  int p = blockIdx.y;
  const float L2E = 1.4426950408889634f;
  if (p == 3) {
#pragma unroll
    for (int j = 0; j < 4; ++j) {
      int chunk = blockIdx.x * 1024 + j * 256 + threadIdx.x;
      int i = chunk * 8;
      f32x4 a = *(const f32x4*)(x + i);
      f32x4 c = *(const f32x4*)(x + i + 4);
      uint4 rv;
      rv.x = (unsigned)f2bf(a[0]) | ((unsigned)f2bf(a[1]) << 16);
      rv.y = (unsigned)f2bf(a[2]) | ((unsigned)f2bf(a[3]) << 16);
      rv.z = (unsigned)f2bf(c[0]) | ((unsigned)f2bf(c[1]) << 16);
      rv.w = (unsigned)f2bf(c[2]) | ((unsigned)f2bf(c[3]) << 16);
      *(uint4*)(Xb + i) = rv;
    }
    if (blockIdx.x < 4) {
      // cfP[b][2048]: exp(mask) in the attn-permuted bf16x8 layout
      int bb = blockIdx.x;
      int j = threadIdx.x;                    // covers keys tile=(j>>2), q8=(j&3)
      int base0 = (j >> 2) * 32 + (j & 3) * 4;
      const float* mpb = mask + bb * T_;
      f32x4 mlo = *(const f32x4*)(mpb + base0);
      f32x4 mhi = *(const f32x4*)(mpb + base0 + 16);
      bf16x8 cf;
#pragma unroll
      for (int r = 0; r < 4; ++r) {
        cf[r]     = (__bf16)exp2f(mlo[r] * L2E);
        cf[4 + r] = (__bf16)exp2f(mhi[r] * L2E);
      }
      *(bf16x8*)(cfP + bb * 2048 + j * 8) = cf;
    }
    return;
  }
  const float* W = (p == 0) ? Wq : (p == 1) ? Wk : Wv;
  const float* A = (p == 0) ? Aq : (p == 1) ? Ak : Av;
  const float* B = (p == 0) ? Bq : (p == 1) ? Bk : Bv;
  int idx4 = (blockIdx.x * 256 + threadIdx.x) * 4;
  int o = idx4 >> 10, h0 = idx4 & 1023;
  f32x4 acc = *(const f32x4*)(W + idx4);
#pragma unroll
  for (int r = 0; r < 8; ++r) {
    float bb = 2.0f * B[o * 8 + r];                  // SCALING = 16/8 = 2
    f32x4 av = *(const f32x4*)(A + r * H_ + h0);
#pragma unroll
    for (int j = 0; j < 4; ++j) acc[j] += bb * av[j];
  }
  uint2 pk;
  pk.x = (unsigned)f2bf(acc[0]) | ((unsigned)f2bf(acc[1]) << 16);
  pk.y = (unsigned)f2bf(acc[2]) | ((unsigned)f2bf(acc[3]) << 16);
  *(uint2*)(Weff + p * (H_ * H_) + idx4) = pk;
}

// ---------------- QKV GEMM: C[m,n] = sum_k Xb[m,k] * Weff[n,k] (+bias) ----------------
// R15 config: BK=64, 2 barriers/step, XOR chunk-swizzled LDS, swapped MFMA,
// XCD-chunked swizzle, __launch_bounds__(256,3) -> 3 blocks/CU.
#define BM 128
#define BN 128
#define BK 64
__global__ __launch_bounds__(256, 3) void gemm_qkv(
    const unsigned short* __restrict__ Xb, const unsigned short* __restrict__ Weff,
    const float* __restrict__ bq, const float* __restrict__ bk, const float* __restrict__ bv,
    const float* __restrict__ mask,
    unsigned short* __restrict__ qq, unsigned short* __restrict__ kk, unsigned short* __restrict__ vP) {
  __shared__ __align__(16) unsigned short As[BM][BK];   // 16 KB
  __shared__ __align__(16) unsigned short Bs[BM][BK];   // 16 KB
  int tid = threadIdx.x;
  int bid = blockIdx.x;                          // 1536
  int xcd = bid & 7, j = bid >> 3;               // XCD-chunked swizzle
  int mt = xcd * 8 + (j & 7);                    // m-tile 0..63
  int ntile = j >> 3;                            // n-tile 0..23
  int m0 = mt * BM;
  int n0 = ntile * BN;
  int w = tid >> 6, l = tid & 63;
  int wm = w >> 1, wn = w & 1;
  int lr = l & 15, lg = l >> 4;
  const float L2E = 1.4426950408889634f;

  f32x4 acc[4][4] = {};
#pragma unroll 1
  for (int kt = 0; kt < H_ / BK; ++kt) {
    __syncthreads();
#pragma unroll
    for (int i2 = 0; i2 < 4; ++i2) {
      int c = tid + i2 * 256;                    // 1024 16B chunks per operand tile
      int row = c >> 3, slot = c & 7;
      int ks = (slot ^ (row & 7)) * 8;           // inverse-swizzled global source
      const unsigned short* ga = Xb + (size_t)(m0 + row) * H_ + kt * BK + ks;
      const unsigned short* gb = Weff + (size_t)(n0 + row) * H_ + kt * BK + ks;
      __builtin_amdgcn_global_load_lds((const __attribute__((address_space(1))) void*)ga,
                                       (__attribute__((address_space(3))) void*)(&As[0][0] + c * 8), 16, 0, 0);
      __builtin_amdgcn_global_load_lds((const __attribute__((address_space(1))) void*)gb,
                                       (__attribute__((address_space(3))) void*)(&Bs[0][0] + c * 8), 16, 0, 0);
    }
    __syncthreads();                             // drain vmcnt: tile ready
#pragma unroll
    for (int kk2 = 0; kk2 < 2; ++kk2) {          // k-slice outer: live regs stay low
      bf16x8 af[4], bf[4];
#pragma unroll
      for (int f = 0; f < 4; ++f) {
        int ra = wm * 64 + f * 16 + lr;
        int rb = wn * 64 + f * 16 + lr;
        int sa = ((kk2 << 2) | lg) ^ (ra & 7);   // swizzled read chunk
        int sb = ((kk2 << 2) | lg) ^ (rb & 7);
        af[f] = *(const bf16x8*)&As[ra][sa * 8];
        bf[f] = *(const bf16x8*)&Bs[rb][sb * 8];
      }
#pragma unroll
      for (int fm = 0; fm < 4; ++fm)
#pragma unroll
        for (int fn = 0; fn < 4; ++fn)           // swapped: lanes=tokens(m), regs=features(n)
          acc[fm][fn] = __builtin_amdgcn_mfma_f32_16x16x32_bf16(bf[fn], af[fm], acc[fm][fn], 0, 0, 0);
    }
  }

  int p = n0 >> 10;
  const float* bias = (p == 0) ? bq : (p == 1) ? bk : bv;
  const float QSCALE = 0.125f * L2E;             // softmax 1/sqrt(64) and log2-base fold
#pragma unroll
  for (int fm = 0; fm < 4; ++fm) {
    int m = m0 + wm * 64 + fm * 16 + lr;
    int bb = m >> 11, t = m & 2047;
    float expm = (p == 2) ? exp2f(mask[(size_t)bb * T_ + t] * L2E) : 1.0f;  // e^{m[k]}
#pragma unroll
    for (int fn = 0; fn < 4; ++fn) {
      int o0 = (n0 & 1023) + wn * 64 + fn * 16 + lg * 4;
      int hh = o0 >> 6, d0 = o0 & 63;
      size_t bh = (size_t)(bb * NH_ + hh);
      f32x4 b4 = *(const f32x4*)(bias + o0);
      if (p == 0) {
        *(uint2*)(qq + (bh * T_ + t) * HD_ + d0) =
          pack4bf((acc[fm][fn][0] + b4[0]) * QSCALE, (acc[fm][fn][1] + b4[1]) * QSCALE,
                  (acc[fm][fn][2] + b4[2]) * QSCALE, (acc[fm][fn][3] + b4[3]) * QSCALE);
      } else if (p == 1) {
        *(uint2*)(kk + (bh * T_ + t) * HD_ + d0) =
          pack4bf(acc[fm][fn][0] + b4[0], acc[fm][fn][1] + b4[1],
                  acc[fm][fn][2] + b4[2], acc[fm][fn][3] + b4[3]);
      } else {
        int r5 = t & 31;
        int within = ((r5 >> 2) & 3) * 8 + (r5 & 3) + ((r5 >> 4) << 2);
        size_t tbase = (size_t)(t & ~31) + within;
#pragma unroll
        for (int r = 0; r < 4; ++r)
          vP[(bh * HD_ + d0 + r) * T_ + tbase] =
            __builtin_bit_cast(unsigned short, (__bf16)((acc[fm][fn][r] + b4[r]) * expm));
      }
    }
  }
}

// ---------------- causal flash attention, LDS K/V, KVBLK=64 ----------------
// R20 structure; micro: hoisted LDS read offsets + staging bases, consolidated
// setprio regions. Base-2 softmax, mask folded into V', l on the MFMA pipe.
__global__ __launch_bounds__(256, 5) void attn_fwd(
    const unsigned short* __restrict__ qq, const unsigned short* __restrict__ kk,
    const unsigned short* __restrict__ vP, const unsigned short* __restrict__ cfP,
    float* __restrict__ out) {
  __shared__ __align__(16) char lds[2][16384];   // [buf][sub0: K4K|V4K | sub1: K4K|V4K] = 32 KB

  int tid = threadIdx.x;
  int w = tid >> 6, l = tid & 63;
  int bid = blockIdx.x;                          // 2048
  int bh = bid & 63;                             // bid%8==bh&7 -> XCD locality
  int i = 31 - (bid >> 6);                       // big groups dispatch first
  int b = bh >> 4, h = bh & 15;
  int lr = l & 15, g8 = l >> 4;
  const float NINF = -__builtin_inff();

  const unsigned short* cfb = cfP + b * 2048;

  // ---- staging lane bases (hoisted: only + k0-dependent term per call) ----
  int krow = tid >> 3, kslot = tid & 7;
  int kgs = kslot ^ (krow & 7);
  int vsub = kgs >> 2, vslot = kgs & 3;
  int vrow = (krow << 1) | vsub;
  const unsigned short* KpL = kk + (size_t)bh * T_ * HD_ + (size_t)krow * HD_ + kgs * 8;
  const unsigned short* VpL = vP + (size_t)bh * HD_ * T_ + (size_t)vrow * T_ + vslot * 8;
  char* ldsK = &lds[0][0] + tid * 16;            // + buf*16384 + sub*8192
  char* ldsV = &lds[0][0] + 4096 + tid * 16;

  auto stage32 = [&](int t32, int dst, int sub) {
    int k0 = t32 * 32;
    __builtin_amdgcn_global_load_lds(
        (const __attribute__((address_space(1))) void*)(KpL + (size_t)k0 * HD_),
        (__attribute__((address_space(3))) void*)(ldsK + dst * 16384 + sub * 8192), 16, 0, 0);
    __builtin_amdgcn_global_load_lds(
        (const __attribute__((address_space(1))) void*)(VpL + k0),
        (__attribute__((address_space(3))) void*)(ldsV + dst * 16384 + sub * 8192), 16, 0, 0);
  };
  auto stage64 = [&](int t64, int dst) { stage32(2 * t64, dst, 0); stage32(2 * t64 + 1, dst, 1); };

  // ---- LDS read offsets (hoisted, loop-invariant) ----
  int kswz = lr & 7;
  int vrd = (lr >> 1) & 7;
  int kOff0[2], kOff1[2], vOff[4];
#pragma unroll
  for (int hs = 0; hs < 2; ++hs) {
    int sl = ((hs << 2) | g8) ^ kswz;
    kOff0[hs] = lr * 128 + (sl << 4);
    kOff1[hs] = (16 + lr) * 128 + (sl << 4);
  }
#pragma unroll
  for (int dn = 0; dn < 4; ++dn) {
    int rowp = dn * 8 + (lr >> 1);
    int sl = (((lr & 1) << 2) | g8) ^ vrd;
    vOff[dn] = 4096 + rowp * 128 + (sl << 4);
  }

  int qt = 4 * i + w;
  int ntmax64 = i + 1;
  int nt = (qt >> 1) + 1;                        // 32-key tiles; nfull == i for all waves
  int dsub = (nt - 1) & 1;
  int t0 = qt * 16;
  const unsigned short* Qp = qq + ((size_t)bh * T_ + t0) * HD_;

  bf16x8 qf[2];
#pragma unroll
  for (int hs = 0; hs < 2; ++hs)
    qf[hs] = *(const bf16x8*)(Qp + lr * HD_ + hs * 32 + g8 * 8);

  f32x4 accO[4] = {};
  f32x4 accL = {};

  auto qk32 = [&](const char* kb, f32x4& s0, f32x4& s1) {
    __builtin_amdgcn_s_setprio(1);
#pragma unroll
    for (int hs = 0; hs < 2; ++hs) {
      bf16x8 kc0 = *(const bf16x8*)(kb + kOff0[hs]);
      bf16x8 kc1 = *(const bf16x8*)(kb + kOff1[hs]);
      s0 = __builtin_amdgcn_mfma_f32_16x16x32_bf16(kc0, qf[hs], s0, 0, 0, 0);
      s1 = __builtin_amdgcn_mfma_f32_16x16x32_bf16(kc1, qf[hs], s1, 0, 0, 0);
    }
    __builtin_amdgcn_s_setprio(0);
  };
  auto pv32 = [&](const char* kb, bf16x8 pv) {
    __builtin_amdgcn_s_setprio(1);
#pragma unroll
    for (int dn = 0; dn < 4; ++dn) {
      bf16x8 vf = *(const bf16x8*)(kb + vOff[dn]);
      accO[dn] = __builtin_amdgcn_mfma_f32_16x16x32_bf16(vf, pv, accO[dn], 0, 0, 0);
    }
    __builtin_amdgcn_s_setprio(0);
  };

  auto step64 = [&](const char* kb0, const char* kb1, int k0) {
    f32x4 sA0 = {}, sA1 = {}, sB0 = {}, sB1 = {};
    qk32(kb0, sA0, sA1);
    qk32(kb1, sB0, sB1);
    bf16x8 pvA, pvB;
#pragma unroll
    for (int r = 0; r < 4; ++r) {
      pvA[r]     = (__bf16)exp2f(sA0[r]);
      pvA[4 + r] = (__bf16)exp2f(sA1[r]);
      pvB[r]     = (__bf16)exp2f(sB0[r]);
      pvB[4 + r] = (__bf16)exp2f(sB1[r]);
    }
    bf16x8 cf0 = *(const bf16x8*)(cfb + (k0 >> 5) * 32 + g8 * 8);
    bf16x8 cf1 = *(const bf16x8*)(cfb + (k0 >> 5) * 32 + 32 + g8 * 8);
    __builtin_amdgcn_s_setprio(1);
    accL = __builtin_amdgcn_mfma_f32_16x16x32_bf16(cf0, pvA, accL, 0, 0, 0);
    accL = __builtin_amdgcn_mfma_f32_16x16x32_bf16(cf1, pvB, accL, 0, 0, 0);
    __builtin_amdgcn_s_setprio(0);
    pv32(kb0, pvA);
    pv32(kb1, pvB);
  };

  auto step32 = [&](const char* kb, int k0, bool diag) {
    f32x4 s0 = {}, s1 = {};
    qk32(kb, s0, s1);
    bf16x8 pv;
    int qrow = t0 + lr;
#pragma unroll
    for (int r = 0; r < 4; ++r) {
      int ka = k0 + g8 * 4 + r;
      float a0 = (!diag || ka <= qrow)      ? s0[r] : NINF;
      float a1 = (!diag || ka + 16 <= qrow) ? s1[r] : NINF;
      pv[r]     = (__bf16)exp2f(a0);
      pv[4 + r] = (__bf16)exp2f(a1);
    }
    bf16x8 cf = *(const bf16x8*)(cfb + (k0 >> 5) * 32 + g8 * 8);
    __builtin_amdgcn_s_setprio(1);
    accL = __builtin_amdgcn_mfma_f32_16x16x32_bf16(cf, pv, accL, 0, 0, 0);
    __builtin_amdgcn_s_setprio(0);
    pv32(kb, pv);
  };

  int buf = 0;
  stage64(0, 0);
  __syncthreads();

#pragma unroll 1
  for (int ti = 0; ti < ntmax64; ++ti) {
    if (ti + 1 < ntmax64) stage64(ti + 1, buf ^ 1);
    const char* kb0 = lds[buf];
    const char* kb1 = lds[buf] + 8192;
    if (ti < ntmax64 - 1) {
      step64(kb0, kb1, ti * 64);
    } else {                                     // ti == nfull == i (all waves)
      if (dsub == 0) {
        step32(kb0, ti * 64, true);
      } else {
        step32(kb0, ti * 64, false);
        step32(kb1, ti * 64 + 32, true);
      }
    }
    __syncthreads();
    buf ^= 1;
  }

  float inv = 1.0f / accL[0];                    // complete per-q sum, all lanes
  float* op = out + ((size_t)b * T_ + t0 + lr) * H_ + h * HD_;
#pragma unroll
  for (int dn = 0; dn < 4; ++dn) {
    f32x4 ov;
#pragma unroll
    for (int r = 0; r < 4; ++r) ov[r] = accO[dn][r] * inv;
    *(f32x4*)(op + dn * 16 + g8 * 4) = ov;
  }
}

extern "C" void kernel_launch(void* const* d_in, const int* in_sizes, int n_in,
                              void* d_out, int out_size, void* d_ws, size_t ws_size,
                              hipStream_t stream) {
  const float* x    = (const float*)d_in[0];
  const float* mask = (const float*)d_in[1];
  const float* Wq = (const float*)d_in[2];
  const float* bq = (const float*)d_in[3];
  const float* Aq = (const float*)d_in[4];
  const float* Bq = (const float*)d_in[5];
  const float* Wk = (const float*)d_in[6];
  const float* bk = (const float*)d_in[7];
  const float* Ak = (const float*)d_in[8];
  const float* Bk = (const float*)d_in[9];
  const float* Wv = (const float*)d_in[10];
  const float* bv = (const float*)d_in[11];
  const float* Av = (const float*)d_in[12];
  const float* Bv = (const float*)d_in[13];
  float* out = (float*)d_out;

  char* ws = (char*)d_ws;
  unsigned short* Xb   = (unsigned short*)(ws);                   // 16 MB  [8192][1024]
  unsigned short* Weff = (unsigned short*)(ws + (16u << 20));     //  6 MB  [3][1024][1024]
  unsigned short* qq   = (unsigned short*)(ws + (22u << 20));     // 16 MB  [4][16][2048][64]
  unsigned short* kk   = (unsigned short*)(ws + (38u << 20));     // 16 MB  [4][16][2048][64]
  unsigned short* vP   = (unsigned short*)(ws + (54u << 20));     // 16 MB  [4][16][64][2048] (permuted, mask-folded)
  unsigned short* cfP  = (unsigned short*)(ws + (70u << 20));     // 16 KB  [4][2048] exp(mask), permuted

  prep_fused<<<dim3(1024, 4), 256, 0, stream>>>(Wq, Aq, Bq, Wk, Ak, Bk, Wv, Av, Bv, x, mask, Weff, Xb, cfP);
  gemm_qkv<<<1536, 256, 0, stream>>>(Xb, Weff, bq, bk, bv, mask, qq, kk, vP);
  attn_fwd<<<2048, 256, 0, stream>>>(qq, kk, vP, cfP, out);
}